// Round 7
// baseline (358.226 us; speedup 1.0000x reference)
//
#include <hip/hip_runtime.h>

typedef __bf16 bf16_t;
typedef bf16_t bf16x8 __attribute__((ext_vector_type(8)));
typedef float f32x4 __attribute__((ext_vector_type(4)));
typedef unsigned short us8 __attribute__((ext_vector_type(8)));

#define DEV static __device__ __forceinline__

DEV unsigned short f2bf(float f) {
  unsigned int x = __float_as_uint(f);
  return (unsigned short)((x + 0x7fffu + ((x >> 16) & 1u)) >> 16);
}

DEV f32x4 mfma16(bf16x8 a, bf16x8 b, f32x4 c) {
  return __builtin_amdgcn_mfma_f32_16x16x32_bf16(a, b, c, 0, 0, 0);
}

DEV void gload_lds16(const void* g, void* l) {
  __builtin_amdgcn_global_load_lds(
      (const __attribute__((address_space(1))) void*)g,
      (__attribute__((address_space(3))) void*)l, 16, 0, 0);
}

// ---------------- weight transpose+convert: src f32 [K][N] -> dst bf16 [N][K]
__global__ __launch_bounds__(256) void wt_transpose(
    const float* __restrict__ src, unsigned short* __restrict__ dst, int K, int N) {
  __shared__ float tile[32][33];
  int bx = blockIdx.x * 32;  // n
  int by = blockIdx.y * 32;  // k
  int tx = threadIdx.x, ty = threadIdx.y;
#pragma unroll
  for (int i = ty; i < 32; i += 8)
    tile[i][tx] = src[(size_t)(by + i) * N + bx + tx];
  __syncthreads();
#pragma unroll
  for (int i = ty; i < 32; i += 8)
    dst[(size_t)(bx + i) * K + by + tx] = f2bf(tile[tx][i]);
}

// ---------------- layernorm: f32 [4096][768] -> bf16 [4096][768]
__global__ __launch_bounds__(256) void ln_kernel(
    const float* __restrict__ x, const float* __restrict__ gw,
    const float* __restrict__ bw, unsigned short* __restrict__ out) {
  int row = blockIdx.x;
  const float* xr = x + (size_t)row * 768;
  int t = threadIdx.x;
  float v0 = xr[t], v1 = xr[t + 256], v2 = xr[t + 512];
  float s = v0 + v1 + v2, sq = v0 * v0 + v1 * v1 + v2 * v2;
#pragma unroll
  for (int m = 1; m < 64; m <<= 1) { s += __shfl_xor(s, m); sq += __shfl_xor(sq, m); }
  __shared__ float ssum[4], ssq[4];
  int wid = t >> 6;
  if ((t & 63) == 0) { ssum[wid] = s; ssq[wid] = sq; }
  __syncthreads();
  s = ssum[0] + ssum[1] + ssum[2] + ssum[3];
  sq = ssq[0] + ssq[1] + ssq[2] + ssq[3];
  float mu = s * (1.f / 768.f);
  float var = sq * (1.f / 768.f) - mu * mu;
  float rstd = rsqrtf(fmaxf(var, 0.f) + 1e-6f);
  unsigned short* orow = out + (size_t)row * 768;
  orow[t]       = f2bf((v0 - mu) * rstd * gw[t]       + bw[t]);
  orow[t + 256] = f2bf((v1 - mu) * rstd * gw[t + 256] + bw[t + 256]);
  orow[t + 512] = f2bf((v2 - mu) * rstd * gw[t + 512] + bw[t + 512]);
}

// ---------------- GEMM: C[M x N] = A[M x K](bf16) @ Bt[N x K]^T(bf16), fused epilogues
// EPI 0: QKV scatter (+bias, q*0.125) -> q/k/v [B][H][N][64] bf16
// EPI 1: +bias +resid -> f32
// EPI 2: +bias, exact gelu -> bf16
// EPI 3: +bias +resid -> f32
template <int EPI>
__global__ __launch_bounds__(256) void gemm_bt(
    const unsigned short* __restrict__ A, const unsigned short* __restrict__ Bt, int K,
    const float* __restrict__ b0p, const float* __restrict__ b1p, const float* __restrict__ b2p,
    const float* __restrict__ resid,
    void* __restrict__ o0, void* __restrict__ o1, void* __restrict__ o2) {
  __shared__ unsigned short lA[128 * 32];
  __shared__ unsigned short lB[128 * 32];
  int tid = threadIdx.x;
  int wid = tid >> 6, lane = tid & 63;
  int bm = blockIdx.y * 128, bn = blockIdx.x * 128;
  int wr = (wid >> 1) * 64, wc = (wid & 1) * 64;

  f32x4 acc[4][4] = {};

  const unsigned short* ga  = A  + (size_t)(bm + (tid >> 2)) * K + (tid & 3) * 8;
  const unsigned short* ga2 = A  + (size_t)(bm + 64 + (tid >> 2)) * K + (tid & 3) * 8;
  const unsigned short* gb  = Bt + (size_t)(bn + (tid >> 2)) * K + (tid & 3) * 8;
  const unsigned short* gb2 = Bt + (size_t)(bn + 64 + (tid >> 2)) * K + (tid & 3) * 8;

  for (int kt = 0; kt < K; kt += 32) {
    __syncthreads();
    gload_lds16(ga,  (char*)lA + wid * 1024);
    gload_lds16(ga2, (char*)lA + 4096 + wid * 1024);
    gload_lds16(gb,  (char*)lB + wid * 1024);
    gload_lds16(gb2, (char*)lB + 4096 + wid * 1024);
    ga += 32; ga2 += 32; gb += 32; gb2 += 32;
    __syncthreads();
    bf16x8 af[4], bfv[4];
#pragma unroll
    for (int mi = 0; mi < 4; mi++)
      af[mi] = *(const bf16x8*)(lA + (wr + mi * 16 + (lane & 15)) * 32 + (lane >> 4) * 8);
#pragma unroll
    for (int ni = 0; ni < 4; ni++)
      bfv[ni] = *(const bf16x8*)(lB + (wc + ni * 16 + (lane & 15)) * 32 + (lane >> 4) * 8);
#pragma unroll
    for (int mi = 0; mi < 4; mi++)
#pragma unroll
      for (int ni = 0; ni < 4; ni++)
        acc[mi][ni] = mfma16(af[mi], bfv[ni], acc[mi][ni]);
  }

  int r0 = bm + wr + ((lane >> 4) << 2);
  int c0 = bn + wc + (lane & 15);
#pragma unroll
  for (int mi = 0; mi < 4; mi++) {
#pragma unroll
    for (int ni = 0; ni < 4; ni++) {
      int col = c0 + ni * 16;
#pragma unroll
      for (int r = 0; r < 4; r++) {
        int row = r0 + mi * 16 + r;
        float val = acc[mi][ni][r];
        if constexpr (EPI == 0) {
          int which = col / 768;
          int rem = col - which * 768;
          int h = rem >> 6, d = rem & 63;
          const float* bias = (which == 0) ? b0p : (which == 1) ? b1p : b2p;
          unsigned short* dst = (unsigned short*)((which == 0) ? o0 : (which == 1) ? o1 : o2);
          val += bias[rem];
          if (which == 0) val *= 0.125f;
          int b = row >> 10, n = row & 1023;
          dst[(((size_t)b * 12 + h) * 1024 + n) * 64 + d] = f2bf(val);
        } else if constexpr (EPI == 1) {
          ((float*)o0)[(size_t)row * 768 + col] = val + b0p[col] + resid[(size_t)row * 768 + col];
        } else if constexpr (EPI == 2) {
          float hv = val + b0p[col];
          float ge = 0.5f * hv * (1.f + erff(hv * 0.70710678118654752f));
          ((unsigned short*)o0)[(size_t)row * 3072 + col] = f2bf(ge);
        } else {
          ((float*)o0)[(size_t)row * 768 + col] = val + b0p[col] + resid[(size_t)row * 768 + col];
        }
      }
    }
  }
}

// ---------------- flash attention: q pre-scaled by 1/8; q,k,v [B*H][1024][64] bf16
__global__ __launch_bounds__(256) void attn_kernel(
    const unsigned short* __restrict__ q, const unsigned short* __restrict__ k,
    const unsigned short* __restrict__ v, unsigned short* __restrict__ ctx) {
  int bh = blockIdx.y;
  int bb = bh / 12, hh = bh % 12;
  int q0 = blockIdx.x * 64;
  int wid = threadIdx.x >> 6, lane = threadIdx.x & 63;
  const size_t head_off = (size_t)bh * 1024 * 64;
  const unsigned short* qh = q + head_off;
  const unsigned short* kh = k + head_off;
  const unsigned short* vh = v + head_off;

  __shared__ unsigned short lK[64 * 64];       // linear, content XOR-swizzled
  __shared__ unsigned short lVt[64][72];       // V^T, padded
  __shared__ unsigned short lP[4][16][72];     // per-wave P buffer, padded

  bf16x8 aq[2];
  {
    int row = q0 + wid * 16 + (lane & 15);
    const unsigned short* qr = qh + (size_t)row * 64 + (lane >> 4) * 8;
    aq[0] = *(const bf16x8*)qr;
    aq[1] = *(const bf16x8*)(qr + 32);
  }
  f32x4 cacc[4] = {};
  float mrow[4], lrow[4];
#pragma unroll
  for (int r = 0; r < 4; r++) { mrow[r] = -1e30f; lrow[r] = 0.f; }

  for (int kt = 0; kt < 16; ++kt) {
    __syncthreads();
    {  // K tile: linear LDS dest, pre-swizzled global source (swz = (row&7)<<4 on row-byte)
      int t = threadIdx.x;
      int row = t >> 3;
      int colb = (t & 7) * 16;
      const unsigned short* g0 = kh + (size_t)(kt * 64 + row) * 64 + ((colb ^ ((row & 7) << 4)) >> 1);
      gload_lds16(g0, (char*)lK + wid * 1024);
      int row2 = row + 32;  // (row2&7)==(row&7)
      const unsigned short* g1 = kh + (size_t)(kt * 64 + row2) * 64 + ((colb ^ ((row & 7) << 4)) >> 1);
      gload_lds16(g1, (char*)lK + 4096 + wid * 1024);
    }
    {  // V tile transposed into lVt via registers
      int kp = threadIdx.x >> 3;        // k-pair 0..31
      int d0 = (threadIdx.x & 7) * 8;
      const unsigned short* vp = vh + (size_t)(kt * 64 + kp * 2) * 64 + d0;
      us8 r0v = *(const us8*)vp;
      us8 r1v = *(const us8*)(vp + 64);
      unsigned int* lv = (unsigned int*)lVt;  // row stride 36 u32
#pragma unroll
      for (int j = 0; j < 8; j++)
        lv[(d0 + j) * 36 + kp] = (unsigned int)r0v[j] | ((unsigned int)r1v[j] << 16);
    }
    __syncthreads();

    // S = (q/8) @ K^T : swizzled reads
    f32x4 sacc[4] = {};
#pragma unroll
    for (int ni = 0; ni < 4; ni++) {
      int krow = ni * 16 + (lane & 15);
      int swz = (krow & 7) << 4;
      const char* base = (const char*)lK + krow * 128;
      bf16x8 b0 = *(const bf16x8*)(base + (((lane >> 4) * 16) ^ swz));
      bf16x8 b1 = *(const bf16x8*)(base + ((64 + (lane >> 4) * 16) ^ swz));
      sacc[ni] = mfma16(aq[0], b0, sacc[ni]);
      sacc[ni] = mfma16(aq[1], b1, sacc[ni]);
    }

    // online softmax; lane holds rows g*4+r (g=lane>>4), col ni*16+(lane&15)
    float pv[4][4];
#pragma unroll
    for (int r = 0; r < 4; r++) {
      float tm = fmaxf(fmaxf(sacc[0][r], sacc[1][r]), fmaxf(sacc[2][r], sacc[3][r]));
#pragma unroll
      for (int m = 1; m < 16; m <<= 1) tm = fmaxf(tm, __shfl_xor(tm, m));
      float mn = fmaxf(mrow[r], tm);
      float corr = __expf(mrow[r] - mn);
      float rs = 0.f;
#pragma unroll
      for (int ni = 0; ni < 4; ni++) {
        float p = __expf(sacc[ni][r] - mn);
        pv[ni][r] = p;
        rs += p;
      }
#pragma unroll
      for (int m = 1; m < 16; m <<= 1) rs += __shfl_xor(rs, m);
      lrow[r] = lrow[r] * corr + rs;
      mrow[r] = mn;
#pragma unroll
      for (int di = 0; di < 4; di++) cacc[di][r] *= corr;
    }

    // P -> per-wave LDS (layout convert D->A)
#pragma unroll
    for (int ni = 0; ni < 4; ni++)
#pragma unroll
      for (int r = 0; r < 4; r++)
        lP[wid][(lane >> 4) * 4 + r][ni * 16 + (lane & 15)] = f2bf(pv[ni][r]);

    // ctx += P @ V
#pragma unroll
    for (int kc = 0; kc < 2; kc++) {
      bf16x8 pa = *(const bf16x8*)&lP[wid][lane & 15][kc * 32 + (lane >> 4) * 8];
#pragma unroll
      for (int di = 0; di < 4; di++) {
        bf16x8 bvv = *(const bf16x8*)&lVt[di * 16 + (lane & 15)][kc * 32 + (lane >> 4) * 8];
        cacc[di] = mfma16(pa, bvv, cacc[di]);
      }
    }
  }

  // finalize: divide by l, stage through lP, write coalesced 16B chunks
#pragma unroll
  for (int di = 0; di < 4; di++)
#pragma unroll
    for (int r = 0; r < 4; r++)
      lP[wid][(lane >> 4) * 4 + r][di * 16 + (lane & 15)] = f2bf(cacc[di][r] / lrow[r]);
  {
    int row = lane >> 2;
    int c0 = (lane & 3) * 16;
    const unsigned short* sp = &lP[wid][row][c0];
    us8 w0 = *(const us8*)sp;
    us8 w1 = *(const us8*)(sp + 8);
    int gq = q0 + wid * 16 + row;
    unsigned short* gp = ctx + ((size_t)(bb * 1024 + gq)) * 768 + hh * 64 + c0;
    *(us8*)gp = w0;
    *(us8*)(gp + 8) = w1;
  }
}

extern "C" void kernel_launch(void* const* d_in, const int* in_sizes, int n_in,
                              void* d_out, int out_size, void* d_ws, size_t ws_size,
                              hipStream_t stream) {
  const float* x    = (const float*)d_in[0];
  const float* ln1g = (const float*)d_in[1];
  const float* ln1b = (const float*)d_in[2];
  const float* Wq   = (const float*)d_in[3];
  const float* bq   = (const float*)d_in[4];
  const float* Wk   = (const float*)d_in[5];
  const float* bk   = (const float*)d_in[6];
  const float* Wv   = (const float*)d_in[7];
  const float* bv   = (const float*)d_in[8];
  const float* Wo   = (const float*)d_in[9];
  const float* bo   = (const float*)d_in[10];
  const float* ln2g = (const float*)d_in[11];
  const float* ln2b = (const float*)d_in[12];
  const float* W1   = (const float*)d_in[13];
  const float* b1   = (const float*)d_in[14];
  const float* W2   = (const float*)d_in[15];
  const float* b2   = (const float*)d_in[16];
  float* out = (float*)d_out;

  char* ws = (char*)d_ws;
  unsigned short* xn    = (unsigned short*)(ws + 0);         // 6,291,456
  float*          x2    = (float*)(ws + 6291456);            // 12,582,912
  unsigned short* x2n   = (unsigned short*)(ws + 18874368);  // 6,291,456
  unsigned short* qws   = (unsigned short*)(ws + 25165824);  // 6,291,456
  unsigned short* kws   = (unsigned short*)(ws + 31457280);  // 6,291,456
  unsigned short* vws   = (unsigned short*)(ws + 37748736);  // 6,291,456
  unsigned short* ctx   = (unsigned short*)(ws + 44040192);  // 6,291,456
  unsigned short* hmid  = (unsigned short*)(ws + 50331648);  // 25,165,824
  unsigned short* Wqkvt = (unsigned short*)(ws + 75497472);  // 3,538,944
  unsigned short* Wot   = (unsigned short*)(ws + 79036416);  // 1,179,648
  unsigned short* W1t   = (unsigned short*)(ws + 80216064);  // 4,718,592
  unsigned short* W2t   = (unsigned short*)(ws + 84934656);  // 4,718,592  (end ~89.7MB)

  dim3 tb(32, 8);
  wt_transpose<<<dim3(24, 24), tb, 0, stream>>>(Wq, Wqkvt, 768, 768);
  wt_transpose<<<dim3(24, 24), tb, 0, stream>>>(Wk, Wqkvt + 589824, 768, 768);
  wt_transpose<<<dim3(24, 24), tb, 0, stream>>>(Wv, Wqkvt + 1179648, 768, 768);
  wt_transpose<<<dim3(24, 24), tb, 0, stream>>>(Wo, Wot, 768, 768);
  wt_transpose<<<dim3(96, 24), tb, 0, stream>>>(W1, W1t, 768, 3072);
  wt_transpose<<<dim3(24, 96), tb, 0, stream>>>(W2, W2t, 3072, 768);

  ln_kernel<<<4096, 256, 0, stream>>>(x, ln1g, ln1b, xn);
  gemm_bt<0><<<dim3(18, 32), 256, 0, stream>>>(xn, Wqkvt, 768, bq, bk, bv, nullptr, qws, kws, vws);
  attn_kernel<<<dim3(16, 48), 256, 0, stream>>>(qws, kws, vws, ctx);
  gemm_bt<1><<<dim3(6, 32), 256, 0, stream>>>(ctx, Wot, 768, bo, nullptr, nullptr, x, x2, nullptr, nullptr);
  ln_kernel<<<4096, 256, 0, stream>>>(x2, ln2g, ln2b, x2n);
  gemm_bt<2><<<dim3(24, 32), 256, 0, stream>>>(x2n, W1t, 768, b1, nullptr, nullptr, nullptr, hmid, nullptr, nullptr);
  gemm_bt<3><<<dim3(6, 32), 256, 0, stream>>>(hmid, W2t, 3072, b2, nullptr, nullptr, x2, out, nullptr, nullptr);
}

// Round 8
// 336.827 us; speedup vs baseline: 1.0635x; 1.0635x over previous
//
#include <hip/hip_runtime.h>

typedef __bf16 bf16_t;
typedef bf16_t bf16x8 __attribute__((ext_vector_type(8)));
typedef float f32x4 __attribute__((ext_vector_type(4)));
typedef unsigned short us8 __attribute__((ext_vector_type(8)));

#define DEV static __device__ __forceinline__

DEV unsigned short f2bf(float f) {
  unsigned int x = __float_as_uint(f);
  return (unsigned short)((x + 0x7fffu + ((x >> 16) & 1u)) >> 16);
}

DEV f32x4 mfma16(bf16x8 a, bf16x8 b, f32x4 c) {
  return __builtin_amdgcn_mfma_f32_16x16x32_bf16(a, b, c, 0, 0, 0);
}

DEV void gload_lds16(const void* g, void* l) {
  __builtin_amdgcn_global_load_lds(
      (const __attribute__((address_space(1))) void*)g,
      (__attribute__((address_space(3))) void*)l, 16, 0, 0);
}

// ---------------- weight transpose+convert: src f32 [K][N] -> dst bf16 [N][K]
__global__ __launch_bounds__(256) void wt_transpose(
    const float* __restrict__ src, unsigned short* __restrict__ dst, int K, int N) {
  __shared__ float tile[32][33];
  int bx = blockIdx.x * 32;  // n
  int by = blockIdx.y * 32;  // k
  int tx = threadIdx.x, ty = threadIdx.y;
#pragma unroll
  for (int i = ty; i < 32; i += 8)
    tile[i][tx] = src[(size_t)(by + i) * N + bx + tx];
  __syncthreads();
#pragma unroll
  for (int i = ty; i < 32; i += 8)
    dst[(size_t)(bx + i) * K + by + tx] = f2bf(tile[tx][i]);
}

// ---------------- layernorm: f32 [4096][768] -> bf16 [4096][768]
__global__ __launch_bounds__(256) void ln_kernel(
    const float* __restrict__ x, const float* __restrict__ gw,
    const float* __restrict__ bw, unsigned short* __restrict__ out) {
  int row = blockIdx.x;
  const float* xr = x + (size_t)row * 768;
  int t = threadIdx.x;
  float v0 = xr[t], v1 = xr[t + 256], v2 = xr[t + 512];
  float s = v0 + v1 + v2, sq = v0 * v0 + v1 * v1 + v2 * v2;
#pragma unroll
  for (int m = 1; m < 64; m <<= 1) { s += __shfl_xor(s, m); sq += __shfl_xor(sq, m); }
  __shared__ float ssum[4], ssq[4];
  int wid = t >> 6;
  if ((t & 63) == 0) { ssum[wid] = s; ssq[wid] = sq; }
  __syncthreads();
  s = ssum[0] + ssum[1] + ssum[2] + ssum[3];
  sq = ssq[0] + ssq[1] + ssq[2] + ssq[3];
  float mu = s * (1.f / 768.f);
  float var = sq * (1.f / 768.f) - mu * mu;
  float rstd = rsqrtf(fmaxf(var, 0.f) + 1e-6f);
  unsigned short* orow = out + (size_t)row * 768;
  orow[t]       = f2bf((v0 - mu) * rstd * gw[t]       + bw[t]);
  orow[t + 256] = f2bf((v1 - mu) * rstd * gw[t + 256] + bw[t + 256]);
  orow[t + 512] = f2bf((v2 - mu) * rstd * gw[t + 512] + bw[t + 512]);
}

// ---------------- GEMM 128x128: C = A @ Bt^T, fused epilogues
// EPI 0: QKV scatter (+bias, q*0.125) -> q/k/v [B][H][N][64] bf16
// EPI 2: +bias, exact gelu -> bf16
template <int EPI>
__global__ __launch_bounds__(256) void gemm_bt(
    const unsigned short* __restrict__ A, const unsigned short* __restrict__ Bt, int K,
    const float* __restrict__ b0p, const float* __restrict__ b1p, const float* __restrict__ b2p,
    void* __restrict__ o0, void* __restrict__ o1, void* __restrict__ o2) {
  __shared__ unsigned short lA[128 * 32];
  __shared__ unsigned short lB[128 * 32];
  int tid = threadIdx.x;
  int wid = tid >> 6, lane = tid & 63;
  int bm = blockIdx.y * 128, bn = blockIdx.x * 128;
  int wr = (wid >> 1) * 64, wc = (wid & 1) * 64;

  f32x4 acc[4][4] = {};

  const unsigned short* ga  = A  + (size_t)(bm + (tid >> 2)) * K + (tid & 3) * 8;
  const unsigned short* ga2 = A  + (size_t)(bm + 64 + (tid >> 2)) * K + (tid & 3) * 8;
  const unsigned short* gb  = Bt + (size_t)(bn + (tid >> 2)) * K + (tid & 3) * 8;
  const unsigned short* gb2 = Bt + (size_t)(bn + 64 + (tid >> 2)) * K + (tid & 3) * 8;

  for (int kt = 0; kt < K; kt += 32) {
    __syncthreads();
    gload_lds16(ga,  (char*)lA + wid * 1024);
    gload_lds16(ga2, (char*)lA + 4096 + wid * 1024);
    gload_lds16(gb,  (char*)lB + wid * 1024);
    gload_lds16(gb2, (char*)lB + 4096 + wid * 1024);
    ga += 32; ga2 += 32; gb += 32; gb2 += 32;
    __syncthreads();
    bf16x8 af[4], bfv[4];
#pragma unroll
    for (int mi = 0; mi < 4; mi++)
      af[mi] = *(const bf16x8*)(lA + (wr + mi * 16 + (lane & 15)) * 32 + (lane >> 4) * 8);
#pragma unroll
    for (int ni = 0; ni < 4; ni++)
      bfv[ni] = *(const bf16x8*)(lB + (wc + ni * 16 + (lane & 15)) * 32 + (lane >> 4) * 8);
#pragma unroll
    for (int mi = 0; mi < 4; mi++)
#pragma unroll
      for (int ni = 0; ni < 4; ni++)
        acc[mi][ni] = mfma16(af[mi], bfv[ni], acc[mi][ni]);
  }

  int r0 = bm + wr + ((lane >> 4) << 2);
  int c0 = bn + wc + (lane & 15);
#pragma unroll
  for (int mi = 0; mi < 4; mi++) {
#pragma unroll
    for (int ni = 0; ni < 4; ni++) {
      int col = c0 + ni * 16;
#pragma unroll
      for (int r = 0; r < 4; r++) {
        int row = r0 + mi * 16 + r;
        float val = acc[mi][ni][r];
        if constexpr (EPI == 0) {
          int which = col / 768;
          int rem = col - which * 768;
          int h = rem >> 6, d = rem & 63;
          const float* bias = (which == 0) ? b0p : (which == 1) ? b1p : b2p;
          unsigned short* dst = (unsigned short*)((which == 0) ? o0 : (which == 1) ? o1 : o2);
          val += bias[rem];
          if (which == 0) val *= 0.125f;
          int b = row >> 10, n = row & 1023;
          dst[(((size_t)b * 12 + h) * 1024 + n) * 64 + d] = f2bf(val);
        } else {
          float hv = val + b0p[col];
          float ge = 0.5f * hv * (1.f + erff(hv * 0.70710678118654752f));
          ((unsigned short*)o0)[(size_t)row * 3072 + col] = f2bf(ge);
        }
      }
    }
  }
}

// ---------------- split-K GEMM: 128(M)x64(N) tile, grid (N/64, M/128, S)
// writes raw f32 partials: part[z][4096][768]
__global__ __launch_bounds__(256) void gemm_sk(
    const unsigned short* __restrict__ A, const unsigned short* __restrict__ Bt,
    int K, int ksplit, float* __restrict__ part) {
  __shared__ unsigned short lA[128 * 32];
  __shared__ unsigned short lB[64 * 32];
  int tid = threadIdx.x;
  int wid = tid >> 6, lane = tid & 63;
  int bm = blockIdx.y * 128, bn = blockIdx.x * 64;
  int k0 = blockIdx.z * ksplit;
  int wr = (wid >> 1) * 64, wc = (wid & 1) * 32;

  f32x4 acc[4][2] = {};

  const unsigned short* ga  = A  + (size_t)(bm + (tid >> 2)) * K + k0 + (tid & 3) * 8;
  const unsigned short* ga2 = A  + (size_t)(bm + 64 + (tid >> 2)) * K + k0 + (tid & 3) * 8;
  const unsigned short* gb  = Bt + (size_t)(bn + (tid >> 2)) * K + k0 + (tid & 3) * 8;

  for (int kt = 0; kt < ksplit; kt += 32) {
    __syncthreads();
    gload_lds16(ga,  (char*)lA + wid * 1024);
    gload_lds16(ga2, (char*)lA + 4096 + wid * 1024);
    gload_lds16(gb,  (char*)lB + wid * 1024);
    ga += 32; ga2 += 32; gb += 32;
    __syncthreads();
    bf16x8 af[4], bfv[2];
#pragma unroll
    for (int mi = 0; mi < 4; mi++)
      af[mi] = *(const bf16x8*)(lA + (wr + mi * 16 + (lane & 15)) * 32 + (lane >> 4) * 8);
#pragma unroll
    for (int ni = 0; ni < 2; ni++)
      bfv[ni] = *(const bf16x8*)(lB + (wc + ni * 16 + (lane & 15)) * 32 + (lane >> 4) * 8);
#pragma unroll
    for (int mi = 0; mi < 4; mi++)
#pragma unroll
      for (int ni = 0; ni < 2; ni++)
        acc[mi][ni] = mfma16(af[mi], bfv[ni], acc[mi][ni]);
  }

  float* pp = part + (size_t)blockIdx.z * (4096 * 768);
  int r0 = bm + wr + ((lane >> 4) << 2);
  int c0 = bn + wc + (lane & 15);
#pragma unroll
  for (int mi = 0; mi < 4; mi++)
#pragma unroll
    for (int ni = 0; ni < 2; ni++)
#pragma unroll
      for (int r = 0; r < 4; r++)
        pp[(size_t)(r0 + mi * 16 + r) * 768 + c0 + ni * 16] = acc[mi][ni][r];
}

// ---------------- split-K reduce + bias + residual -> f32 out (vectorized f32x4)
__global__ __launch_bounds__(256) void skred(
    const float* __restrict__ part, const float* __restrict__ bias,
    const float* __restrict__ resid, float* __restrict__ out) {
  int i = blockIdx.x * 256 + threadIdx.x;  // float4 index, total 786432
  const f32x4* p0 = (const f32x4*)part;
  const f32x4* p1 = p0 + 786432;
  const f32x4* rz = (const f32x4*)resid;
  const f32x4* bz = (const f32x4*)bias;
  f32x4 v = p0[i] + p1[i] + bz[i % 192] + rz[i];
  ((f32x4*)out)[i] = v;
}

// ---------------- flash attention: q pre-scaled by 1/8; q,k,v [B*H][1024][64] bf16
__global__ __launch_bounds__(256) void attn_kernel(
    const unsigned short* __restrict__ q, const unsigned short* __restrict__ k,
    const unsigned short* __restrict__ v, unsigned short* __restrict__ ctx) {
  int bh = blockIdx.y;
  int bb = bh / 12, hh = bh % 12;
  int q0 = blockIdx.x * 64;
  int wid = threadIdx.x >> 6, lane = threadIdx.x & 63;
  const size_t head_off = (size_t)bh * 1024 * 64;
  const unsigned short* qh = q + head_off;
  const unsigned short* kh = k + head_off;
  const unsigned short* vh = v + head_off;

  __shared__ unsigned short lK[64 * 64];       // linear, content XOR-swizzled
  __shared__ unsigned short lVt[64][72];       // V^T, padded
  __shared__ unsigned short lP[4][16][72];     // per-wave P buffer, padded

  bf16x8 aq[2];
  {
    int row = q0 + wid * 16 + (lane & 15);
    const unsigned short* qr = qh + (size_t)row * 64 + (lane >> 4) * 8;
    aq[0] = *(const bf16x8*)qr;
    aq[1] = *(const bf16x8*)(qr + 32);
  }
  f32x4 cacc[4] = {};
  float mrow[4], lrow[4];
#pragma unroll
  for (int r = 0; r < 4; r++) { mrow[r] = -1e30f; lrow[r] = 0.f; }

  for (int kt = 0; kt < 16; ++kt) {
    __syncthreads();
    {  // K tile: linear LDS dest, pre-swizzled global source (swz = (row&7)<<4 on row-byte)
      int t = threadIdx.x;
      int row = t >> 3;
      int colb = (t & 7) * 16;
      const unsigned short* g0 = kh + (size_t)(kt * 64 + row) * 64 + ((colb ^ ((row & 7) << 4)) >> 1);
      gload_lds16(g0, (char*)lK + wid * 1024);
      int row2 = row + 32;  // (row2&7)==(row&7)
      const unsigned short* g1 = kh + (size_t)(kt * 64 + row2) * 64 + ((colb ^ ((row & 7) << 4)) >> 1);
      gload_lds16(g1, (char*)lK + 4096 + wid * 1024);
    }
    {  // V tile transposed into lVt via registers
      int kp = threadIdx.x >> 3;        // k-pair 0..31
      int d0 = (threadIdx.x & 7) * 8;
      const unsigned short* vp = vh + (size_t)(kt * 64 + kp * 2) * 64 + d0;
      us8 r0v = *(const us8*)vp;
      us8 r1v = *(const us8*)(vp + 64);
      unsigned int* lv = (unsigned int*)lVt;  // row stride 36 u32
#pragma unroll
      for (int j = 0; j < 8; j++)
        lv[(d0 + j) * 36 + kp] = (unsigned int)r0v[j] | ((unsigned int)r1v[j] << 16);
    }
    __syncthreads();

    // S = (q/8) @ K^T : swizzled reads
    f32x4 sacc[4] = {};
#pragma unroll
    for (int ni = 0; ni < 4; ni++) {
      int krow = ni * 16 + (lane & 15);
      int swz = (krow & 7) << 4;
      const char* base = (const char*)lK + krow * 128;
      bf16x8 b0 = *(const bf16x8*)(base + (((lane >> 4) * 16) ^ swz));
      bf16x8 b1 = *(const bf16x8*)(base + ((64 + (lane >> 4) * 16) ^ swz));
      sacc[ni] = mfma16(aq[0], b0, sacc[ni]);
      sacc[ni] = mfma16(aq[1], b1, sacc[ni]);
    }

    // online softmax; lane holds rows g*4+r (g=lane>>4), col ni*16+(lane&15)
    float pv[4][4];
#pragma unroll
    for (int r = 0; r < 4; r++) {
      float tm = fmaxf(fmaxf(sacc[0][r], sacc[1][r]), fmaxf(sacc[2][r], sacc[3][r]));
#pragma unroll
      for (int m = 1; m < 16; m <<= 1) tm = fmaxf(tm, __shfl_xor(tm, m));
      float mn = fmaxf(mrow[r], tm);
      float corr = __expf(mrow[r] - mn);
      float rs = 0.f;
#pragma unroll
      for (int ni = 0; ni < 4; ni++) {
        float p = __expf(sacc[ni][r] - mn);
        pv[ni][r] = p;
        rs += p;
      }
#pragma unroll
      for (int m = 1; m < 16; m <<= 1) rs += __shfl_xor(rs, m);
      lrow[r] = lrow[r] * corr + rs;
      mrow[r] = mn;
#pragma unroll
      for (int di = 0; di < 4; di++) cacc[di][r] *= corr;
    }

    // P -> per-wave LDS (layout convert D->A)
#pragma unroll
    for (int ni = 0; ni < 4; ni++)
#pragma unroll
      for (int r = 0; r < 4; r++)
        lP[wid][(lane >> 4) * 4 + r][ni * 16 + (lane & 15)] = f2bf(pv[ni][r]);

    // ctx += P @ V
#pragma unroll
    for (int kc = 0; kc < 2; kc++) {
      bf16x8 pa = *(const bf16x8*)&lP[wid][lane & 15][kc * 32 + (lane >> 4) * 8];
#pragma unroll
      for (int di = 0; di < 4; di++) {
        bf16x8 bvv = *(const bf16x8*)&lVt[di * 16 + (lane & 15)][kc * 32 + (lane >> 4) * 8];
        cacc[di] = mfma16(pa, bvv, cacc[di]);
      }
    }
  }

  // finalize: divide by l, stage through lP, write coalesced 16B chunks
#pragma unroll
  for (int di = 0; di < 4; di++)
#pragma unroll
    for (int r = 0; r < 4; r++)
      lP[wid][(lane >> 4) * 4 + r][di * 16 + (lane & 15)] = f2bf(cacc[di][r] / lrow[r]);
  {
    int row = lane >> 2;
    int c0 = (lane & 3) * 16;
    const unsigned short* sp = &lP[wid][row][c0];
    us8 w0 = *(const us8*)sp;
    us8 w1 = *(const us8*)(sp + 8);
    int gq = q0 + wid * 16 + row;
    unsigned short* gp = ctx + ((size_t)(bb * 1024 + gq)) * 768 + hh * 64 + c0;
    *(us8*)gp = w0;
    *(us8*)(gp + 8) = w1;
  }
}

extern "C" void kernel_launch(void* const* d_in, const int* in_sizes, int n_in,
                              void* d_out, int out_size, void* d_ws, size_t ws_size,
                              hipStream_t stream) {
  const float* x    = (const float*)d_in[0];
  const float* ln1g = (const float*)d_in[1];
  const float* ln1b = (const float*)d_in[2];
  const float* Wq   = (const float*)d_in[3];
  const float* bq   = (const float*)d_in[4];
  const float* Wk   = (const float*)d_in[5];
  const float* bk   = (const float*)d_in[6];
  const float* Wv   = (const float*)d_in[7];
  const float* bv   = (const float*)d_in[8];
  const float* Wo   = (const float*)d_in[9];
  const float* bo   = (const float*)d_in[10];
  const float* ln2g = (const float*)d_in[11];
  const float* ln2b = (const float*)d_in[12];
  const float* W1   = (const float*)d_in[13];
  const float* b1   = (const float*)d_in[14];
  const float* W2   = (const float*)d_in[15];
  const float* b2   = (const float*)d_in[16];
  float* out = (float*)d_out;

  char* ws = (char*)d_ws;
  // [0 .. 25165824) doubles as split-K partial slab (part lifetime disjoint
  // from xn/q/k/v: part1 written after attn consumed qkv; part2 after that)
  unsigned short* xn    = (unsigned short*)(ws + 0);         // 6,291,456
  unsigned short* qws   = (unsigned short*)(ws + 6291456);   // 6,291,456
  unsigned short* kws   = (unsigned short*)(ws + 12582912);  // 6,291,456
  unsigned short* vws   = (unsigned short*)(ws + 18874368);  // 6,291,456
  float*          part  = (float*)(ws + 0);                  // 25,165,824 (overlay)
  unsigned short* ctx   = (unsigned short*)(ws + 25165824);  // 6,291,456
  float*          x2    = (float*)(ws + 31457280);           // 12,582,912
  unsigned short* x2n   = (unsigned short*)(ws + 44040192);  // 6,291,456
  unsigned short* hmid  = (unsigned short*)(ws + 50331648);  // 25,165,824
  unsigned short* Wqkvt = (unsigned short*)(ws + 75497472);  // 3,538,944
  unsigned short* Wot   = (unsigned short*)(ws + 79036416);  // 1,179,648
  unsigned short* W1t   = (unsigned short*)(ws + 80216064);  // 4,718,592
  unsigned short* W2t   = (unsigned short*)(ws + 84934656);  // 4,718,592  (end ~89.7MB)

  dim3 tb(32, 8);
  wt_transpose<<<dim3(24, 24), tb, 0, stream>>>(Wq, Wqkvt, 768, 768);
  wt_transpose<<<dim3(24, 24), tb, 0, stream>>>(Wk, Wqkvt + 589824, 768, 768);
  wt_transpose<<<dim3(24, 24), tb, 0, stream>>>(Wv, Wqkvt + 1179648, 768, 768);
  wt_transpose<<<dim3(24, 24), tb, 0, stream>>>(Wo, Wot, 768, 768);
  wt_transpose<<<dim3(96, 24), tb, 0, stream>>>(W1, W1t, 768, 3072);
  wt_transpose<<<dim3(24, 96), tb, 0, stream>>>(W2, W2t, 3072, 768);

  ln_kernel<<<4096, 256, 0, stream>>>(x, ln1g, ln1b, xn);
  gemm_bt<0><<<dim3(18, 32), 256, 0, stream>>>(xn, Wqkvt, 768, bq, bk, bv, qws, kws, vws);
  attn_kernel<<<dim3(16, 48), 256, 0, stream>>>(qws, kws, vws, ctx);
  // Wo projection: split-K=2 (K=768 -> 384/block), 768 blocks
  gemm_sk<<<dim3(12, 32, 2), 256, 0, stream>>>(ctx, Wot, 768, 384, part);
  skred<<<3072, 256, 0, stream>>>(part, bo, x, x2);
  ln_kernel<<<4096, 256, 0, stream>>>(x2, ln2g, ln2b, x2n);
  gemm_bt<2><<<dim3(24, 32), 256, 0, stream>>>(x2n, W1t, 768, b1, nullptr, nullptr, hmid, nullptr, nullptr);
  // W2 projection: split-K=2 (K=3072 -> 1536/block), 768 blocks
  gemm_sk<<<dim3(12, 32, 2), 256, 0, stream>>>(hmid, W2t, 3072, 1536, part);
  skred<<<3072, 256, 0, stream>>>(part, b2, x2, out);
}

// Round 10
// 331.688 us; speedup vs baseline: 1.0800x; 1.0155x over previous
//
#include <hip/hip_runtime.h>

typedef __bf16 bf16_t;
typedef bf16_t bf16x8 __attribute__((ext_vector_type(8)));
typedef float f32x4 __attribute__((ext_vector_type(4)));
typedef unsigned short us8 __attribute__((ext_vector_type(8)));

#define DEV static __device__ __forceinline__

DEV unsigned short f2bf(float f) {
  unsigned int x = __float_as_uint(f);
  return (unsigned short)((x + 0x7fffu + ((x >> 16) & 1u)) >> 16);
}

DEV f32x4 mfma16(bf16x8 a, bf16x8 b, f32x4 c) {
  return __builtin_amdgcn_mfma_f32_16x16x32_bf16(a, b, c, 0, 0, 0);
}

DEV void gload_lds16(const void* g, void* l) {
  __builtin_amdgcn_global_load_lds(
      (const __attribute__((address_space(1))) void*)g,
      (__attribute__((address_space(3))) void*)l, 16, 0, 0);
}

// ---------------- weight transpose+convert: src f32 [K][N] -> dst bf16 [N][K]
__global__ __launch_bounds__(256) void wt_transpose(
    const float* __restrict__ src, unsigned short* __restrict__ dst, int K, int N) {
  __shared__ float tile[32][33];
  int bx = blockIdx.x * 32;  // n
  int by = blockIdx.y * 32;  // k
  int tx = threadIdx.x, ty = threadIdx.y;
#pragma unroll
  for (int i = ty; i < 32; i += 8)
    tile[i][tx] = src[(size_t)(by + i) * N + bx + tx];
  __syncthreads();
#pragma unroll
  for (int i = ty; i < 32; i += 8)
    dst[(size_t)(bx + i) * K + by + tx] = f2bf(tile[tx][i]);
}

// ---------------- layernorm: f32 [4096][768] -> bf16 [4096][768]
__global__ __launch_bounds__(256) void ln_kernel(
    const float* __restrict__ x, const float* __restrict__ gw,
    const float* __restrict__ bw, unsigned short* __restrict__ out) {
  int row = blockIdx.x;
  const float* xr = x + (size_t)row * 768;
  int t = threadIdx.x;
  float v0 = xr[t], v1 = xr[t + 256], v2 = xr[t + 512];
  float s = v0 + v1 + v2, sq = v0 * v0 + v1 * v1 + v2 * v2;
#pragma unroll
  for (int m = 1; m < 64; m <<= 1) { s += __shfl_xor(s, m); sq += __shfl_xor(sq, m); }
  __shared__ float ssum[4], ssq[4];
  int wid = t >> 6;
  if ((t & 63) == 0) { ssum[wid] = s; ssq[wid] = sq; }
  __syncthreads();
  s = ssum[0] + ssum[1] + ssum[2] + ssum[3];
  sq = ssq[0] + ssq[1] + ssq[2] + ssq[3];
  float mu = s * (1.f / 768.f);
  float var = sq * (1.f / 768.f) - mu * mu;
  float rstd = rsqrtf(fmaxf(var, 0.f) + 1e-6f);
  unsigned short* orow = out + (size_t)row * 768;
  orow[t]       = f2bf((v0 - mu) * rstd * gw[t]       + bw[t]);
  orow[t + 256] = f2bf((v1 - mu) * rstd * gw[t + 256] + bw[t + 256]);
  orow[t + 512] = f2bf((v2 - mu) * rstd * gw[t + 512] + bw[t + 512]);
}

// ---------------- GEMM 128x128: C = A @ Bt^T, fused epilogues
// EPI 0: QKV scatter (+bias, q*0.125) -> q/k/v [B][H][N][64] bf16
// EPI 2: +bias, exact gelu -> bf16
template <int EPI>
__global__ __launch_bounds__(256) void gemm_bt(
    const unsigned short* __restrict__ A, const unsigned short* __restrict__ Bt, int K,
    const float* __restrict__ b0p, const float* __restrict__ b1p, const float* __restrict__ b2p,
    void* __restrict__ o0, void* __restrict__ o1, void* __restrict__ o2) {
  __shared__ unsigned short lA[128 * 32];
  __shared__ unsigned short lB[128 * 32];
  int tid = threadIdx.x;
  int wid = tid >> 6, lane = tid & 63;
  int bm = blockIdx.y * 128, bn = blockIdx.x * 128;
  int wr = (wid >> 1) * 64, wc = (wid & 1) * 64;

  f32x4 acc[4][4] = {};

  const unsigned short* ga  = A  + (size_t)(bm + (tid >> 2)) * K + (tid & 3) * 8;
  const unsigned short* ga2 = A  + (size_t)(bm + 64 + (tid >> 2)) * K + (tid & 3) * 8;
  const unsigned short* gb  = Bt + (size_t)(bn + (tid >> 2)) * K + (tid & 3) * 8;
  const unsigned short* gb2 = Bt + (size_t)(bn + 64 + (tid >> 2)) * K + (tid & 3) * 8;

  for (int kt = 0; kt < K; kt += 32) {
    __syncthreads();
    gload_lds16(ga,  (char*)lA + wid * 1024);
    gload_lds16(ga2, (char*)lA + 4096 + wid * 1024);
    gload_lds16(gb,  (char*)lB + wid * 1024);
    gload_lds16(gb2, (char*)lB + 4096 + wid * 1024);
    ga += 32; ga2 += 32; gb += 32; gb2 += 32;
    __syncthreads();
    bf16x8 af[4], bfv[4];
#pragma unroll
    for (int mi = 0; mi < 4; mi++)
      af[mi] = *(const bf16x8*)(lA + (wr + mi * 16 + (lane & 15)) * 32 + (lane >> 4) * 8);
#pragma unroll
    for (int ni = 0; ni < 4; ni++)
      bfv[ni] = *(const bf16x8*)(lB + (wc + ni * 16 + (lane & 15)) * 32 + (lane >> 4) * 8);
#pragma unroll
    for (int mi = 0; mi < 4; mi++)
#pragma unroll
      for (int ni = 0; ni < 4; ni++)
        acc[mi][ni] = mfma16(af[mi], bfv[ni], acc[mi][ni]);
  }

  int r0 = bm + wr + ((lane >> 4) << 2);
  int c0 = bn + wc + (lane & 15);
#pragma unroll
  for (int mi = 0; mi < 4; mi++) {
#pragma unroll
    for (int ni = 0; ni < 4; ni++) {
      int col = c0 + ni * 16;
#pragma unroll
      for (int r = 0; r < 4; r++) {
        int row = r0 + mi * 16 + r;
        float val = acc[mi][ni][r];
        if constexpr (EPI == 0) {
          int which = col / 768;
          int rem = col - which * 768;
          int h = rem >> 6, d = rem & 63;
          const float* bias = (which == 0) ? b0p : (which == 1) ? b1p : b2p;
          unsigned short* dst = (unsigned short*)((which == 0) ? o0 : (which == 1) ? o1 : o2);
          val += bias[rem];
          if (which == 0) val *= 0.125f;
          int b = row >> 10, n = row & 1023;
          dst[(((size_t)b * 12 + h) * 1024 + n) * 64 + d] = f2bf(val);
        } else {
          float hv = val + b0p[col];
          float ge = 0.5f * hv * (1.f + erff(hv * 0.70710678118654752f));
          ((unsigned short*)o0)[(size_t)row * 3072 + col] = f2bf(ge);
        }
      }
    }
  }
}

// ---------------- split-K GEMM: 128(M)x64(N) tile, grid (N/64, M/128, S)
// writes raw f32 partials: part[z][4096][768]
__global__ __launch_bounds__(256) void gemm_sk(
    const unsigned short* __restrict__ A, const unsigned short* __restrict__ Bt,
    int K, int ksplit, float* __restrict__ part) {
  __shared__ unsigned short lA[128 * 32];
  __shared__ unsigned short lB[64 * 32];
  int tid = threadIdx.x;
  int wid = tid >> 6, lane = tid & 63;
  int bm = blockIdx.y * 128, bn = blockIdx.x * 64;
  int k0 = blockIdx.z * ksplit;
  int wr = (wid >> 1) * 64, wc = (wid & 1) * 32;

  f32x4 acc[4][2] = {};

  const unsigned short* ga  = A  + (size_t)(bm + (tid >> 2)) * K + k0 + (tid & 3) * 8;
  const unsigned short* ga2 = A  + (size_t)(bm + 64 + (tid >> 2)) * K + k0 + (tid & 3) * 8;
  const unsigned short* gb  = Bt + (size_t)(bn + (tid >> 2)) * K + k0 + (tid & 3) * 8;

  for (int kt = 0; kt < ksplit; kt += 32) {
    __syncthreads();
    gload_lds16(ga,  (char*)lA + wid * 1024);
    gload_lds16(ga2, (char*)lA + 4096 + wid * 1024);
    gload_lds16(gb,  (char*)lB + wid * 1024);
    ga += 32; ga2 += 32; gb += 32;
    __syncthreads();
    bf16x8 af[4], bfv[2];
#pragma unroll
    for (int mi = 0; mi < 4; mi++)
      af[mi] = *(const bf16x8*)(lA + (wr + mi * 16 + (lane & 15)) * 32 + (lane >> 4) * 8);
#pragma unroll
    for (int ni = 0; ni < 2; ni++)
      bfv[ni] = *(const bf16x8*)(lB + (wc + ni * 16 + (lane & 15)) * 32 + (lane >> 4) * 8);
#pragma unroll
    for (int mi = 0; mi < 4; mi++)
#pragma unroll
      for (int ni = 0; ni < 2; ni++)
        acc[mi][ni] = mfma16(af[mi], bfv[ni], acc[mi][ni]);
  }

  float* pp = part + (size_t)blockIdx.z * (4096 * 768);
  int r0 = bm + wr + ((lane >> 4) << 2);
  int c0 = bn + wc + (lane & 15);
#pragma unroll
  for (int mi = 0; mi < 4; mi++)
#pragma unroll
    for (int ni = 0; ni < 2; ni++)
#pragma unroll
      for (int r = 0; r < 4; r++)
        pp[(size_t)(r0 + mi * 16 + r) * 768 + c0 + ni * 16] = acc[mi][ni][r];
}

// ---------------- split-K reduce + bias + residual -> f32 out (vectorized f32x4)
__global__ __launch_bounds__(256) void skred(
    const float* __restrict__ part, const float* __restrict__ bias,
    const float* __restrict__ resid, float* __restrict__ out) {
  int i = blockIdx.x * 256 + threadIdx.x;  // float4 index, total 786432
  const f32x4* p0 = (const f32x4*)part;
  const f32x4* p1 = p0 + 786432;
  const f32x4* rz = (const f32x4*)resid;
  const f32x4* bz = (const f32x4*)bias;
  f32x4 v = p0[i] + p1[i] + bz[i % 192] + rz[i];
  ((f32x4*)out)[i] = v;
}

// ---------------- flash attention: q pre-scaled by 1/8; q,k,v [B*H][1024][64] bf16
// 8 waves: waves 0-3 = kv[0,512), waves 4-7 = kv[512,1024); in-LDS flash merge.
__global__ __launch_bounds__(512) void attn_kernel(
    const unsigned short* __restrict__ q, const unsigned short* __restrict__ k,
    const unsigned short* __restrict__ v, unsigned short* __restrict__ ctx) {
  // smem map: [0,16384) lK (2 groups x 8KB, XOR-swz content)
  //           [16384,32768) lVt (2 groups x 8KB, V^T XOR-swz)
  //           [32768,51200) lP (8 waves x 16x72 u16)
  //           merge buf overlays [0, 25600) after main loop (barrier-separated)
  __shared__ __align__(16) char smem[51200];
  int bh = blockIdx.y;
  int bb = bh / 12, hh = bh % 12;
  int q0 = blockIdx.x * 64;
  int tid = threadIdx.x;
  int wid = tid >> 6, lane = tid & 63;
  int grp = wid >> 2, wq = wid & 3;
  int tg = tid & 255;
  const size_t head_off = (size_t)bh * 1024 * 64;
  const unsigned short* qh = q + head_off;
  const unsigned short* kh = k + head_off + (size_t)grp * 512 * 64;
  const unsigned short* vh = v + head_off + (size_t)grp * 512 * 64;

  unsigned short* lK  = (unsigned short*)smem + grp * 4096;
  unsigned short* lVt = (unsigned short*)(smem + 16384) + grp * 4096;
  unsigned short* lPw = (unsigned short*)(smem + 32768) + wid * 1152;  // 16x72

  bf16x8 aq[2];
  {
    int row = q0 + wq * 16 + (lane & 15);
    const unsigned short* qr = qh + (size_t)row * 64 + (lane >> 4) * 8;
    aq[0] = *(const bf16x8*)qr;
    aq[1] = *(const bf16x8*)(qr + 32);
  }
  f32x4 cacc[4] = {};
  float mrow[4], lrow[4];
#pragma unroll
  for (int r = 0; r < 4; r++) { mrow[r] = -1e30f; lrow[r] = 0.f; }

  for (int kt = 0; kt < 8; ++kt) {
    __syncthreads();
    {  // K tile: linear LDS dest, pre-swizzled global source (swz = (row&7)<<4 on row-byte)
      int row = tg >> 3;
      int colb = (tg & 7) * 16;
      int sw = (colb ^ ((row & 7) << 4)) >> 1;
      const unsigned short* g0 = kh + (size_t)(kt * 64 + row) * 64 + sw;
      gload_lds16(g0, (char*)lK + wq * 1024);
      const unsigned short* g1 = kh + (size_t)(kt * 64 + row + 32) * 64 + sw;  // (row+32)&7 == row&7
      gload_lds16(g1, (char*)lK + 4096 + wq * 1024);
    }
    {  // V tile transposed into lVt (XOR-swizzled: u32idx = d*32 + (kp ^ ((d>>3)&7)<<2))
      int kp = tg >> 3;             // k-pair 0..31
      int d0 = (tg & 7) * 8;
      const unsigned short* vp = vh + (size_t)(kt * 64 + kp * 2) * 64 + d0;
      us8 r0v = *(const us8*)vp;
      us8 r1v = *(const us8*)(vp + 64);
      unsigned int* lv = (unsigned int*)lVt;
#pragma unroll
      for (int j = 0; j < 8; j++) {
        int d = d0 + j;
        lv[d * 32 + (kp ^ ((((d >> 3) & 7)) << 2))] =
            (unsigned int)r0v[j] | ((unsigned int)r1v[j] << 16);
      }
    }
    __syncthreads();

    // S = (q/8) @ K^T : swizzled reads
    f32x4 sacc[4] = {};
#pragma unroll
    for (int ni = 0; ni < 4; ni++) {
      int krow = ni * 16 + (lane & 15);
      int swz = (krow & 7) << 4;
      const char* base = (const char*)lK + krow * 128;
      bf16x8 b0 = *(const bf16x8*)(base + (((lane >> 4) * 16) ^ swz));
      bf16x8 b1 = *(const bf16x8*)(base + ((64 + (lane >> 4) * 16) ^ swz));
      sacc[ni] = mfma16(aq[0], b0, sacc[ni]);
      sacc[ni] = mfma16(aq[1], b1, sacc[ni]);
    }

    // online softmax; lane holds rows g*4+r (g=lane>>4), col ni*16+(lane&15)
    float pv[4][4];
#pragma unroll
    for (int r = 0; r < 4; r++) {
      float tm = fmaxf(fmaxf(sacc[0][r], sacc[1][r]), fmaxf(sacc[2][r], sacc[3][r]));
#pragma unroll
      for (int m = 1; m < 16; m <<= 1) tm = fmaxf(tm, __shfl_xor(tm, m));
      float mn = fmaxf(mrow[r], tm);
      float corr = __expf(mrow[r] - mn);
      float rs = 0.f;
#pragma unroll
      for (int ni = 0; ni < 4; ni++) {
        float p = __expf(sacc[ni][r] - mn);
        pv[ni][r] = p;
        rs += p;
      }
#pragma unroll
      for (int m = 1; m < 16; m <<= 1) rs += __shfl_xor(rs, m);
      lrow[r] = lrow[r] * corr + rs;
      mrow[r] = mn;
#pragma unroll
      for (int di = 0; di < 4; di++) cacc[di][r] *= corr;
    }

    // P -> per-wave LDS (layout convert D->A)
#pragma unroll
    for (int ni = 0; ni < 4; ni++)
#pragma unroll
      for (int r = 0; r < 4; r++)
        lPw[((lane >> 4) * 4 + r) * 72 + ni * 16 + (lane & 15)] = f2bf(pv[ni][r]);

    // ctx += P @ V
#pragma unroll
    for (int kc = 0; kc < 2; kc++) {
      bf16x8 pa = *(const bf16x8*)(lPw + (lane & 15) * 72 + kc * 32 + (lane >> 4) * 8);
#pragma unroll
      for (int di = 0; di < 4; di++) {
        int row = di * 16 + (lane & 15);
        int colu = (kc * 32 + (lane >> 4) * 8) ^ ((((row >> 3) & 7)) << 3);
        bf16x8 bvv = *(const bf16x8*)(lVt + row * 64 + colu);
        cacc[di] = mfma16(pa, bvv, cacc[di]);
      }
    }
  }

  // ---- flash merge of the two kv halves (through padded LDS, stride 25 f32)
  __syncthreads();
  float* mb = (float*)smem;
  float* p = mb + (wq * 64 + lane) * 25;
  if (grp == 1) {
#pragma unroll
    for (int di = 0; di < 4; di++)
#pragma unroll
      for (int r = 0; r < 4; r++) p[di * 4 + r] = cacc[di][r];
#pragma unroll
    for (int r = 0; r < 4; r++) { p[16 + r] = mrow[r]; p[20 + r] = lrow[r]; }
  }
  __syncthreads();
  if (grp == 0) {
#pragma unroll
    for (int r = 0; r < 4; r++) {
      float m1 = p[16 + r], l1 = p[20 + r];
      float M = fmaxf(mrow[r], m1);
      float a0 = __expf(mrow[r] - M), a1 = __expf(m1 - M);
      lrow[r] = a0 * lrow[r] + a1 * l1;
#pragma unroll
      for (int di = 0; di < 4; di++)
        cacc[di][r] = a0 * cacc[di][r] + a1 * p[di * 4 + r];
    }
    // finalize: divide by l, stage through lPw, write coalesced 16B chunks
#pragma unroll
    for (int di = 0; di < 4; di++)
#pragma unroll
      for (int r = 0; r < 4; r++)
        lPw[((lane >> 4) * 4 + r) * 72 + di * 16 + (lane & 15)] = f2bf(cacc[di][r] / lrow[r]);
    int row = lane >> 2;
    int c0 = (lane & 3) * 16;
    const unsigned short* sp = lPw + row * 72 + c0;
    us8 w0 = *(const us8*)sp;
    us8 w1 = *(const us8*)(sp + 8);
    int gq = q0 + wq * 16 + row;
    unsigned short* gp = ctx + ((size_t)(bb * 1024 + gq)) * 768 + hh * 64 + c0;
    *(us8*)gp = w0;
    *(us8*)(gp + 8) = w1;
  }
}

extern "C" void kernel_launch(void* const* d_in, const int* in_sizes, int n_in,
                              void* d_out, int out_size, void* d_ws, size_t ws_size,
                              hipStream_t stream) {
  const float* x    = (const float*)d_in[0];
  const float* ln1g = (const float*)d_in[1];
  const float* ln1b = (const float*)d_in[2];
  const float* Wq   = (const float*)d_in[3];
  const float* bq   = (const float*)d_in[4];
  const float* Wk   = (const float*)d_in[5];
  const float* bk   = (const float*)d_in[6];
  const float* Wv   = (const float*)d_in[7];
  const float* bv   = (const float*)d_in[8];
  const float* Wo   = (const float*)d_in[9];
  const float* bo   = (const float*)d_in[10];
  const float* ln2g = (const float*)d_in[11];
  const float* ln2b = (const float*)d_in[12];
  const float* W1   = (const float*)d_in[13];
  const float* b1   = (const float*)d_in[14];
  const float* W2   = (const float*)d_in[15];
  const float* b2   = (const float*)d_in[16];
  float* out = (float*)d_out;

  char* ws = (char*)d_ws;
  // [0 .. 25165824) doubles as split-K partial slab (part lifetime disjoint
  // from xn/q/k/v: part1 written after attn consumed qkv; part2 after that)
  unsigned short* xn    = (unsigned short*)(ws + 0);         // 6,291,456
  unsigned short* qws   = (unsigned short*)(ws + 6291456);   // 6,291,456
  unsigned short* kws   = (unsigned short*)(ws + 12582912);  // 6,291,456
  unsigned short* vws   = (unsigned short*)(ws + 18874368);  // 6,291,456
  float*          part  = (float*)(ws + 0);                  // 25,165,824 (overlay)
  unsigned short* ctx   = (unsigned short*)(ws + 25165824);  // 6,291,456
  float*          x2    = (float*)(ws + 31457280);           // 12,582,912
  unsigned short* x2n   = (unsigned short*)(ws + 44040192);  // 6,291,456
  unsigned short* hmid  = (unsigned short*)(ws + 50331648);  // 25,165,824
  unsigned short* Wqkvt = (unsigned short*)(ws + 75497472);  // 3,538,944
  unsigned short* Wot   = (unsigned short*)(ws + 79036416);  // 1,179,648
  unsigned short* W1t   = (unsigned short*)(ws + 80216064);  // 4,718,592
  unsigned short* W2t   = (unsigned short*)(ws + 84934656);  // 4,718,592  (end ~89.7MB)

  dim3 tb(32, 8);
  wt_transpose<<<dim3(24, 24), tb, 0, stream>>>(Wq, Wqkvt, 768, 768);
  wt_transpose<<<dim3(24, 24), tb, 0, stream>>>(Wk, Wqkvt + 589824, 768, 768);
  wt_transpose<<<dim3(24, 24), tb, 0, stream>>>(Wv, Wqkvt + 1179648, 768, 768);
  wt_transpose<<<dim3(24, 24), tb, 0, stream>>>(Wo, Wot, 768, 768);
  wt_transpose<<<dim3(96, 24), tb, 0, stream>>>(W1, W1t, 768, 3072);
  wt_transpose<<<dim3(24, 96), tb, 0, stream>>>(W2, W2t, 3072, 768);

  ln_kernel<<<4096, 256, 0, stream>>>(x, ln1g, ln1b, xn);
  gemm_bt<0><<<dim3(18, 32), 256, 0, stream>>>(xn, Wqkvt, 768, bq, bk, bv, qws, kws, vws);
  attn_kernel<<<dim3(16, 48), 512, 0, stream>>>(qws, kws, vws, ctx);
  // Wo projection: split-K=2 (K=768 -> 384/block), 768 blocks
  gemm_sk<<<dim3(12, 32, 2), 256, 0, stream>>>(ctx, Wot, 768, 384, part);
  skred<<<3072, 256, 0, stream>>>(part, bo, x, x2);
  ln_kernel<<<4096, 256, 0, stream>>>(x2, ln2g, ln2b, x2n);
  gemm_bt<2><<<dim3(24, 32), 256, 0, stream>>>(x2n, W1t, 768, b1, nullptr, nullptr, hmid, nullptr, nullptr);
  // W2 projection: split-K=2 (K=3072 -> 1536/block), 768 blocks
  gemm_sk<<<dim3(12, 32, 2), 256, 0, stream>>>(hmid, W2t, 3072, 1536, part);
  skred<<<3072, 256, 0, stream>>>(part, b2, x2, out);
}